// Round 1
// baseline (198.932 us; speedup 1.0000x reference)
//
#include <hip/hip_runtime.h>

#define HH 128
#define WW 128
#define NB 2
#define CI 64
#define CO 64
#define SLS 584  // LDS row stride in bf16 elems (576 + 8 pad: breaks 32-bank alias)

typedef __attribute__((ext_vector_type(8))) short short8;
typedef __attribute__((ext_vector_type(4))) float floatx4;

__device__ __forceinline__ unsigned short f2bf(float f) {
  union { float f; unsigned u; } uu; uu.f = f;
  unsigned r = uu.u + 0x7FFFu + ((uu.u >> 16) & 1u);  // RNE
  return (unsigned short)(r >> 16);
}

// Build bf16 A[o][k*64+c] = weight[o][c][k] * gamma/sqrt(var+eps); bias2 = (bias-mean)*inv+beta
__global__ __launch_bounds__(256) void prep_kernel(
    const float* __restrict__ weight, const float* __restrict__ bias,
    const float* __restrict__ gamma, const float* __restrict__ beta,
    const float* __restrict__ mean, const float* __restrict__ var,
    unsigned short* __restrict__ A, float* __restrict__ bias2) {
  int idx = blockIdx.x * 256 + threadIdx.x;
  if (idx >= CO * 576) return;
  int o = idx / 576, kc = idx - o * 576;
  int k = kc >> 6, c = kc & 63;
  float inv = gamma[o] * rsqrtf(var[o] + 1e-5f);
  A[idx] = f2bf(weight[(o * CI + c) * 9 + k] * inv);
  if (kc == 0) bias2[o] = (bias[o] - mean[o]) * inv + beta[o];
}

// NCHW -> NHWC transpose (64c x 64w tiles via LDS, both sides coalesced)
__global__ __launch_bounds__(256) void transpose_kernel(
    const float* __restrict__ x, float* __restrict__ xT) {
  __shared__ float tile[64][65];
  int bid = blockIdx.x;
  int w0 = (bid & 1) * 64;
  int h = (bid >> 1) & (HH - 1);
  int b = bid >> 8;
  int tc = threadIdx.x & 63;
  int tr = threadIdx.x >> 6;
#pragma unroll
  for (int i = 0; i < 16; i++) {
    int c = i * 4 + tr;
    tile[c][tc] = x[((b * CI + c) * HH + h) * WW + w0 + tc];
  }
  __syncthreads();
#pragma unroll
  for (int i = 0; i < 16; i++) {
    int j = i * 4 + tr;
    xT[((b * HH + h) * WW + w0 + j) * CI + tc] = tile[tc][j];
  }
}

// Offset conv: om[b][oc][h][w], oc in [0,27). Block = one (b,h,ocg) row, 128 w-threads.
__global__ __launch_bounds__(128) void offconv_kernel(
    const float* __restrict__ x, const float* __restrict__ w_off,
    const float* __restrict__ b_off, float* __restrict__ om) {
  int ocg = blockIdx.x;  // 0..2 -> oc = ocg*9 .. +8
  int h = blockIdx.y;
  int b = blockIdx.z;
  int w = threadIdx.x;
  float acc[9];
#pragma unroll
  for (int j = 0; j < 9; j++) acc[j] = 0.f;
  for (int ci = 0; ci < CI; ci++) {
    const float* xp = x + ((b * CI + ci) * HH) * WW;
#pragma unroll
    for (int kh = 0; kh < 3; kh++) {
      int y = h + kh - 1;
      if ((unsigned)y < (unsigned)HH) {
        const float* row = xp + y * WW;
        float xl = (w > 0) ? row[w - 1] : 0.f;
        float xc = row[w];
        float xr = (w < WW - 1) ? row[w + 1] : 0.f;
        const float* wp = w_off + ((ocg * 9) * CI + ci) * 9 + kh * 3;
#pragma unroll
        for (int j = 0; j < 9; j++) {  // block-uniform weight addrs -> s_load
          acc[j] += xl * wp[j * 576] + xc * wp[j * 576 + 1] + xr * wp[j * 576 + 2];
        }
      }
    }
  }
#pragma unroll
  for (int j = 0; j < 9; j++) {
    int oc = ocg * 9 + j;
    om[((b * 27 + oc) * HH + h) * WW + w] = acc[j] + b_off[oc];
  }
}

__device__ __forceinline__ float gat(const float* __restrict__ xb, int y, int xx, int c) {
  int yc = min(max(y, 0), HH - 1);
  int xc = min(max(xx, 0), WW - 1);
  float v = xb[(yc * WW + xc) * CI + c];
  bool ok = ((unsigned)y < (unsigned)HH) && ((unsigned)xx < (unsigned)WW);
  return ok ? v : 0.f;
}

// Fused: bilinear sample (NHWC, coalesced over c) -> LDS bf16 -> MFMA einsum -> BN+ReLU
// Block = 16 pixels (one (b,h), w0..w0+15), 256 threads = 4 waves.
__global__ __launch_bounds__(256) void dcn_kernel(
    const float* __restrict__ xT, const float* __restrict__ om,
    const unsigned short* __restrict__ A, const float* __restrict__ bias2,
    float* __restrict__ out) {
  __shared__ unsigned short SL[16 * SLS];  // S^T[p][k*64+c], bf16
  int bid = blockIdx.x;
  int w0 = (bid & 7) * 16;
  int h = (bid >> 3) & (HH - 1);
  int b = bid >> 10;
  int tid = threadIdx.x;
  int lane = tid & 63;
  int wave = tid >> 6;
  int c = lane;
  int pq = __builtin_amdgcn_readfirstlane(wave);  // force scalar om addressing
  const float* xb = xT + b * HH * WW * CI;
#pragma unroll
  for (int i = 0; i < 4; i++) {
    int p = pq * 4 + i;
    int wpx = w0 + p;
    const float* omp = om + ((b * 27) * HH + h) * WW + wpx;  // uniform -> s_load
#pragma unroll
    for (int k = 0; k < 9; k++) {
      float oy = omp[(2 * k) * HH * WW];
      float ox = omp[(2 * k + 1) * HH * WW];
      float mm = omp[(18 + k) * HH * WW];
      float msk = 1.f / (1.f + __expf(-mm));
      float py = (float)(h - 1 + (k / 3)) + oy;
      float px = (float)(wpx - 1 + (k % 3)) + ox;
      float y0f = floorf(py), x0f = floorf(px);
      float ly = py - y0f, lx = px - x0f;
      int y0 = (int)y0f, x0 = (int)x0f;
      float lylx = ly * lx;
      float w11 = lylx * msk;
      float w10 = (ly - lylx) * msk;
      float w01 = (lx - lylx) * msk;
      float w00 = (1.f - ly - lx + lylx) * msk;
      float v00 = gat(xb, y0, x0, c);
      float v01 = gat(xb, y0, x0 + 1, c);
      float v10 = gat(xb, y0 + 1, x0, c);
      float v11 = gat(xb, y0 + 1, x0 + 1, c);
      float s = w00 * v00 + w01 * v01 + w10 * v10 + w11 * v11;
      SL[p * SLS + k * 64 + c] = f2bf(s);
    }
  }
  __syncthreads();
  // Each wave: 16x16 output tile (o = wave*16..+15, p = 0..15), K = 576.
  floatx4 acc = {0.f, 0.f, 0.f, 0.f};
  int r16 = lane & 15;
  int quad = lane >> 4;
  const unsigned short* Ap = A + (wave * 16 + r16) * 576 + quad * 8;  // A[m=lane&15][k=quad*8+j]
  const unsigned short* Sp = &SL[r16 * SLS + quad * 8];               // B[k=quad*8+j][n=lane&15]
#pragma unroll
  for (int kc0 = 0; kc0 < 576; kc0 += 32) {
    short8 av = *(const short8*)(Ap + kc0);
    short8 bv = *(const short8*)(Sp + kc0);
    acc = __builtin_amdgcn_mfma_f32_16x16x32_bf16(av, bv, acc, 0, 0, 0);
  }
  // D: n(=p) = lane&15, m(=o_local) = quad*4 + reg
  int p = r16;
#pragma unroll
  for (int r = 0; r < 4; r++) {
    int o = wave * 16 + quad * 4 + r;
    float v = acc[r] + bias2[o];
    out[((b * CO + o) * HH + h) * WW + w0 + p] = fmaxf(v, 0.f);
  }
}

extern "C" void kernel_launch(void* const* d_in, const int* in_sizes, int n_in,
                              void* d_out, int out_size, void* d_ws, size_t ws_size,
                              hipStream_t stream) {
  const float* x = (const float*)d_in[0];
  const float* w_off = (const float*)d_in[1];
  const float* b_off = (const float*)d_in[2];
  const float* weight = (const float*)d_in[3];
  const float* bias = (const float*)d_in[4];
  const float* gamma = (const float*)d_in[5];
  const float* beta = (const float*)d_in[6];
  const float* run_mean = (const float*)d_in[7];
  const float* run_var = (const float*)d_in[8];
  float* outp = (float*)d_out;

  char* ws = (char*)d_ws;
  float* xT = (float*)ws;                                        // 8,388,608 B
  float* om = (float*)(ws + 8388608);                            // 3,538,944 B
  unsigned short* A = (unsigned short*)(ws + 8388608 + 3538944); //    73,728 B
  float* bias2 = (float*)(ws + 8388608 + 3538944 + 73728);       //       256 B

  prep_kernel<<<144, 256, 0, stream>>>(weight, bias, gamma, beta, run_mean, run_var, A, bias2);
  transpose_kernel<<<512, 256, 0, stream>>>(x, xT);
  offconv_kernel<<<dim3(3, HH, NB), 128, 0, stream>>>(x, w_off, b_off, om);
  dcn_kernel<<<2048, 256, 0, stream>>>(xT, om, A, bias2, outp);
}

// Round 2
// 140.723 us; speedup vs baseline: 1.4136x; 1.4136x over previous
//
#include <hip/hip_runtime.h>

#define HH 128
#define WW 128
#define NB 2
#define CI 64
#define CO 64
#define SLS 584  // LDS row stride in bf16 elems (576 + 8 pad)

typedef __attribute__((ext_vector_type(8))) short short8;
typedef __attribute__((ext_vector_type(4))) float floatx4;

__device__ __forceinline__ unsigned short f2bf(float f) {
  union { float f; unsigned u; } uu; uu.f = f;
  unsigned r = uu.u + 0x7FFFu + ((uu.u >> 16) & 1u);  // RNE
  return (unsigned short)(r >> 16);
}

// Build:
//  A[o][k*64+c]  = weight[o][c][k] * gamma/sqrt(var+eps)      (bf16, 64x576)
//  w2[o][kk*64+c] = w_off[o][c][kk] for o<27, 0 for 27..31    (bf16, 32x576)
//  bias2[o]      = (bias-mean)*inv + beta
__global__ __launch_bounds__(256) void prep_kernel(
    const float* __restrict__ weight, const float* __restrict__ bias,
    const float* __restrict__ gamma, const float* __restrict__ beta,
    const float* __restrict__ mean, const float* __restrict__ var,
    const float* __restrict__ w_off,
    unsigned short* __restrict__ A, unsigned short* __restrict__ w2,
    float* __restrict__ bias2) {
  int idx = blockIdx.x * 256 + threadIdx.x;
  if (idx >= CO * 576) return;
  int o = idx / 576, kc = idx - o * 576;
  int k = kc >> 6, c = kc & 63;
  float inv = gamma[o] * rsqrtf(var[o] + 1e-5f);
  A[idx] = f2bf(weight[(o * CI + c) * 9 + k] * inv);
  if (kc == 0) bias2[o] = (bias[o] - mean[o]) * inv + beta[o];
  if (o < 32) w2[idx] = (o < 27) ? f2bf(w_off[o * 576 + c * 9 + k]) : (unsigned short)0;
}

// NCHW -> NHWC transpose (64c x 64w tiles via LDS, both sides coalesced)
__global__ __launch_bounds__(256) void transpose_kernel(
    const float* __restrict__ x, float* __restrict__ xT) {
  __shared__ float tile[64][65];
  int bid = blockIdx.x;
  int w0 = (bid & 1) * 64;
  int h = (bid >> 1) & (HH - 1);
  int b = bid >> 8;
  int tc = threadIdx.x & 63;
  int tr = threadIdx.x >> 6;
#pragma unroll
  for (int i = 0; i < 16; i++) {
    int c = i * 4 + tr;
    tile[c][tc] = x[((b * CI + c) * HH + h) * WW + w0 + tc];
  }
  __syncthreads();
#pragma unroll
  for (int i = 0; i < 16; i++) {
    int j = i * 4 + tr;
    xT[((b * HH + h) * WW + w0 + j) * CI + tc] = tile[tc][j];
  }
}

__device__ __forceinline__ float gat(const float* __restrict__ xb, int y, int xx, int c) {
  int yc = min(max(y, 0), HH - 1);
  int xc = min(max(xx, 0), WW - 1);
  float v = xb[(yc * WW + xc) * CI + c];
  bool ok = ((unsigned)y < (unsigned)HH) && ((unsigned)xx < (unsigned)WW);
  return ok ? v : 0.f;
}

// Fully fused: im2col X -> MFMA offset-conv -> offsets/mask in LDS ->
// bilinear sample -> LDS bf16 -> MFMA einsum -> BN + ReLU.
// Block = 16 pixels (one (b,h), w0..w0+15), 256 threads = 4 waves.
__global__ __launch_bounds__(256) void dcn2_kernel(
    const float* __restrict__ xT, const unsigned short* __restrict__ w2,
    const float* __restrict__ b_off, const unsigned short* __restrict__ A,
    const float* __restrict__ bias2, float* __restrict__ out) {
  __shared__ unsigned short SL[16 * SLS];  // phase 1: X patches; phase 3: sampled S
  __shared__ float omS[16 * 29];           // per-pixel 27 offset-conv outputs (stride 29)
  int bid = blockIdx.x;
  int w0 = (bid & 7) * 16;
  int h = (bid >> 3) & (HH - 1);
  int b = bid >> 10;
  int tid = threadIdx.x;
  int lane = tid & 63;
  int wave = tid >> 6;
  int c = lane;
  const float* xb = xT + b * HH * WW * CI;

  // ---- Phase 1: stage im2col patches X[p][kk*64+c] (bf16, coalesced) ----
#pragma unroll
  for (int i = 0; i < 4; i++) {
    int p = wave * 4 + i;
    int wpx = w0 + p;
#pragma unroll
    for (int kk = 0; kk < 9; kk++) {
      int y = h - 1 + kk / 3;
      int xx = wpx - 1 + kk % 3;
      bool ok = ((unsigned)y < (unsigned)HH) && ((unsigned)xx < (unsigned)WW);
      float v = ok ? xb[(y * WW + xx) * CI + c] : 0.f;
      SL[p * SLS + kk * 64 + c] = f2bf(v);
    }
  }
  __syncthreads();

  int r16 = lane & 15;
  int quad = lane >> 4;

  // ---- Phase 2: offset conv via MFMA (waves 0,1 compute oc tiles 0-15,16-31) ----
  if (wave < 2) {
    floatx4 acc2 = {0.f, 0.f, 0.f, 0.f};
    const unsigned short* Ap2 = w2 + (wave * 16 + r16) * 576 + quad * 8;
    const unsigned short* Sp2 = &SL[r16 * SLS + quad * 8];
#pragma unroll
    for (int kc0 = 0; kc0 < 576; kc0 += 32) {
      short8 av = *(const short8*)(Ap2 + kc0);
      short8 bv = *(const short8*)(Sp2 + kc0);
      acc2 = __builtin_amdgcn_mfma_f32_16x16x32_bf16(av, bv, acc2, 0, 0, 0);
    }
#pragma unroll
    for (int r = 0; r < 4; r++) {
      int oc = wave * 16 + quad * 4 + r;
      if (oc < 27) omS[r16 * 29 + oc] = acc2[r] + b_off[oc];
    }
  }
  __syncthreads();

  // ---- Phase 3: bilinear sampling, offsets from LDS broadcast ----
#pragma unroll
  for (int i = 0; i < 4; i++) {
    int p = wave * 4 + i;
    int wpx = w0 + p;
#pragma unroll
    for (int k = 0; k < 9; k++) {
      float oy = omS[p * 29 + 2 * k];
      float ox = omS[p * 29 + 2 * k + 1];
      float mm = omS[p * 29 + 18 + k];
      float msk = 1.f / (1.f + __expf(-mm));
      float py = (float)(h - 1 + (k / 3)) + oy;
      float px = (float)(wpx - 1 + (k % 3)) + ox;
      float y0f = floorf(py), x0f = floorf(px);
      float ly = py - y0f, lx = px - x0f;
      int y0 = (int)y0f, x0 = (int)x0f;
      float lylx = ly * lx;
      float w11 = lylx * msk;
      float w10 = (ly - lylx) * msk;
      float w01 = (lx - lylx) * msk;
      float w00 = (1.f - ly - lx + lylx) * msk;
      float v00 = gat(xb, y0, x0, c);
      float v01 = gat(xb, y0, x0 + 1, c);
      float v10 = gat(xb, y0 + 1, x0, c);
      float v11 = gat(xb, y0 + 1, x0 + 1, c);
      float s = w00 * v00 + w01 * v01 + w10 * v10 + w11 * v11;
      SL[p * SLS + k * 64 + c] = f2bf(s);
    }
  }
  __syncthreads();

  // ---- Phase 4: main einsum via MFMA, BN + ReLU epilogue ----
  floatx4 acc = {0.f, 0.f, 0.f, 0.f};
  const unsigned short* Ap = A + (wave * 16 + r16) * 576 + quad * 8;
  const unsigned short* Sp = &SL[r16 * SLS + quad * 8];
#pragma unroll
  for (int kc0 = 0; kc0 < 576; kc0 += 32) {
    short8 av = *(const short8*)(Ap + kc0);
    short8 bv = *(const short8*)(Sp + kc0);
    acc = __builtin_amdgcn_mfma_f32_16x16x32_bf16(av, bv, acc, 0, 0, 0);
  }
  int p = r16;
#pragma unroll
  for (int r = 0; r < 4; r++) {
    int o = wave * 16 + quad * 4 + r;
    float v = acc[r] + bias2[o];
    out[((b * CO + o) * HH + h) * WW + w0 + p] = fmaxf(v, 0.f);
  }
}

extern "C" void kernel_launch(void* const* d_in, const int* in_sizes, int n_in,
                              void* d_out, int out_size, void* d_ws, size_t ws_size,
                              hipStream_t stream) {
  const float* x = (const float*)d_in[0];
  const float* w_off = (const float*)d_in[1];
  const float* b_off = (const float*)d_in[2];
  const float* weight = (const float*)d_in[3];
  const float* bias = (const float*)d_in[4];
  const float* gamma = (const float*)d_in[5];
  const float* beta = (const float*)d_in[6];
  const float* run_mean = (const float*)d_in[7];
  const float* run_var = (const float*)d_in[8];
  float* outp = (float*)d_out;

  char* ws = (char*)d_ws;
  float* xT = (float*)ws;                                  // 8,388,608 B
  unsigned short* A = (unsigned short*)(ws + 8388608);     //    73,728 B
  unsigned short* w2 = (unsigned short*)(ws + 8462336);    //    36,864 B
  float* bias2 = (float*)(ws + 8499200);                   //       256 B

  prep_kernel<<<144, 256, 0, stream>>>(weight, bias, gamma, beta, run_mean, run_var,
                                       w_off, A, w2, bias2);
  transpose_kernel<<<512, 256, 0, stream>>>(x, xT);
  dcn2_kernel<<<2048, 256, 0, stream>>>(xT, w2, b_off, A, bias2, outp);
}